// Round 9
// baseline (95.435 us; speedup 1.0000x reference)
//
#include <hip/hip_runtime.h>
#include <math.h>

// Problem constants
#define NROWS 16384                     // B*S
#define HIDDEN 1024
#define NVARS 320
#define NCOLS 640
#define CVDIM 256
#define OUT_ELEMS (NROWS * CVDIM)

typedef __attribute__((ext_vector_type(8))) short short8;
typedef __attribute__((ext_vector_type(4))) float floatx4;

__device__ __forceinline__ unsigned f32_to_bf16(float f) {
    unsigned u = __builtin_bit_cast(unsigned, f);
    return (u + 0x7FFFu + ((u >> 16) & 1u)) >> 16;
}
__device__ __forceinline__ float bf16_to_f32(ushort u) {
    return __builtin_bit_cast(float, ((unsigned)u) << 16);
}

__global__ __launch_bounds__(256) void convert_bf16_kernel(
    const float* __restrict__ src, ushort* __restrict__ dst, int n8)
{
    const int i = blockIdx.x * 256 + threadIdx.x;
    if (i >= n8) return;
    const float4* s = reinterpret_cast<const float4*>(src) + (size_t)i * 2;
    const float4 v0 = s[0];
    const float4 v1 = s[1];
    uint4 p;
    p.x = f32_to_bf16(v0.x) | (f32_to_bf16(v0.y) << 16);
    p.y = f32_to_bf16(v0.z) | (f32_to_bf16(v0.w) << 16);
    p.z = f32_to_bf16(v1.x) | (f32_to_bf16(v1.y) << 16);
    p.w = f32_to_bf16(v1.z) | (f32_to_bf16(v1.w) << 16);
    reinterpret_cast<uint4*>(dst)[i] = p;
}

__device__ __forceinline__ void async16(const ushort* g, ushort* l) {
    __builtin_amdgcn_global_load_lds(
        (const __attribute__((address_space(1))) void*)g,
        (__attribute__((address_space(3))) void*)l,
        16, 0, 0);
}

// ---------------- GEMM: logits(bf16) = X(f32) @ Wbf^T + bias ----------------
// 128x128x32 tile, 256 threads = 4 waves (2x2), wave tile 64x64.
// A: f32 reg-staged -> bf16 ds_write; B: global_load_lds. Double-buffered,
// issue -> compute -> sync order (loads fly under MFMA).
#define GBM 128
#define GBN 128
#define GBK 32

__global__ __launch_bounds__(256, 3) void gemm_logits_kernel(
    const float* __restrict__ X,        // [16384,1024] f32
    const ushort* __restrict__ Wbf,     // [640,1024] bf16
    const float* __restrict__ bias,     // [640]
    ushort* __restrict__ Lg)            // [16384,640] bf16
{
    __shared__ __align__(16) ushort lds[16384];   // A0 A1 B0 B1, 4096 ush each

    const int tid = threadIdx.x;
    const int lane = tid & 63;
    const int w = tid >> 6;
    const int wm = w >> 1, wn = w & 1;

    // XCD chunked swizzle: 640 blocks, 8 XCDs x 80; within an XCD walk n fastest
    const int bid = blockIdx.x;
    const int wg = (bid & 7) * 80 + (bid >> 3);
    const int m0 = (wg / 5) * GBM;
    const int n0 = (wg % 5) * GBN;

    const int rm = lane & 15;
    const int kc = lane >> 4;

    floatx4 acc[4][4];
#pragma unroll
    for (int i = 0; i < 4; ++i)
#pragma unroll
        for (int j = 0; j < 4; ++j) acc[i][j] = (floatx4){0.f, 0.f, 0.f, 0.f};

    // A staging: row = tid>>1 (2 thr/row), 16 f32 at (tid&1)*16
    const int arow = tid >> 1;
    const int acol = (tid & 1) * 16;
    const float* Aptr = X + (size_t)(m0 + arow) * HIDDEN + acol;

    float4 a0, a1, a2, a3;
#define LOAD_A(kk) { const float* p = Aptr + (kk);                             \
    a0 = *(const float4*)(p);      a1 = *(const float4*)(p + 4);               \
    a2 = *(const float4*)(p + 8);  a3 = *(const float4*)(p + 12); }

#define WRITE_A(dst) { uint4 lo, hi;                                           \
    lo.x = f32_to_bf16(a0.x) | (f32_to_bf16(a0.y) << 16);                      \
    lo.y = f32_to_bf16(a0.z) | (f32_to_bf16(a0.w) << 16);                      \
    lo.z = f32_to_bf16(a1.x) | (f32_to_bf16(a1.y) << 16);                      \
    lo.w = f32_to_bf16(a1.z) | (f32_to_bf16(a1.w) << 16);                      \
    hi.x = f32_to_bf16(a2.x) | (f32_to_bf16(a2.y) << 16);                      \
    hi.y = f32_to_bf16(a2.z) | (f32_to_bf16(a2.w) << 16);                      \
    hi.z = f32_to_bf16(a3.x) | (f32_to_bf16(a3.y) << 16);                      \
    hi.w = f32_to_bf16(a3.z) | (f32_to_bf16(a3.w) << 16);                      \
    uint4* d = (uint4*)((char*)(dst) + arow * 64 + acol * 2);                  \
    d[0] = lo; d[1] = hi; }

#define ISSUE_B(dst, kk) {                                                     \
    int c = tid;                                                               \
    async16(Wbf + (size_t)(n0 + (c >> 2)) * HIDDEN + (kk) + (c & 3) * 8,       \
            (dst) + c * 8);                                                    \
    c = tid + 256;                                                             \
    async16(Wbf + (size_t)(n0 + (c >> 2)) * HIDDEN + (kk) + (c & 3) * 8,       \
            (dst) + c * 8); }

    // prologue
    LOAD_A(0);
    WRITE_A(lds);
    ISSUE_B(lds + 8192, 0);
    LOAD_A(GBK);
    __syncthreads();

    for (int t = 0; t < 32; ++t) {
        const int cur = t & 1;
        ushort* Ac = lds + (cur ? 4096 : 0);
        ushort* An = lds + (cur ? 0 : 4096);
        ushort* Bc = lds + (cur ? 12288 : 8192);
        ushort* Bn = lds + (cur ? 8192 : 12288);
        if (t < 31) {
            WRITE_A(An);
            ISSUE_B(Bn, (t + 1) * GBK);
        }
        if (t < 30) LOAD_A((t + 2) * GBK);

        const short8* Asv = reinterpret_cast<const short8*>(Ac);
        const short8* Bsv = reinterpret_cast<const short8*>(Bc);
        short8 af[4], bf[4];
#pragma unroll
        for (int f = 0; f < 4; ++f) {
            af[f] = Asv[(wm * 64 + f * 16 + rm) * 4 + kc];
            bf[f] = Bsv[(wn * 64 + f * 16 + rm) * 4 + kc];
        }
#pragma unroll
        for (int i = 0; i < 4; ++i)
#pragma unroll
            for (int j = 0; j < 4; ++j)
                acc[i][j] = __builtin_amdgcn_mfma_f32_16x16x32_bf16(
                    af[i], bf[j], acc[i][j], 0, 0, 0);
        __syncthreads();   // drains this step's prefetch (overlapped w/ compute)
    }

    // epilogue: bias, cvt bf16, pair-pack via shfl, uint stores (even lanes)
    const int cl = lane & 15;
    const int r4 = (lane >> 4) * 4;
    float bj[4];
#pragma unroll
    for (int j = 0; j < 4; ++j) bj[j] = bias[n0 + wn * 64 + j * 16 + cl];

#pragma unroll
    for (int i = 0; i < 4; ++i)
#pragma unroll
        for (int j = 0; j < 4; ++j) {
            const int col = n0 + wn * 64 + j * 16 + cl;
#pragma unroll
            for (int q = 0; q < 4; ++q) {
                const int row = m0 + wm * 64 + i * 16 + r4 + q;
                unsigned v = f32_to_bf16(acc[i][j][q] + bj[j]);
                unsigned o = (unsigned)__shfl_xor((int)v, 1);
                if ((cl & 1) == 0)
                    *reinterpret_cast<uint*>(Lg + (size_t)row * NCOLS + col) =
                        v | (o << 16);
            }
        }
}

// ---------------- Quantize: gumbel-argmax / gather / softmax-marginal ----------------
// 32768 logit-rows; block = 32 rows (4 waves x 8). Fully parallel, no inter-task deps.
__global__ __launch_bounds__(256) void quantize_kernel(
    const ushort* __restrict__ Lg,      // [16384,640] bf16
    const float* __restrict__ gu,       // [32768,320]
    const float* __restrict__ cv,       // [640,128]
    float* __restrict__ out,            // [16384,256]
    float* __restrict__ marginal)       // [640]
{
    __shared__ float smr[4][NVARS];
    const int tid = threadIdx.x;
    const int w = tid >> 6;
    const int lane = tid & 63;

    float macc[5];
#pragma unroll
    for (int j = 0; j < 5; ++j) macc[j] = 0.f;

    const int g = w & 1;               // each wave's rows share one group

#pragma unroll
    for (int t = 0; t < 8; ++t) {
        const int r = blockIdx.x * 32 + t * 4 + w;   // logit-row id
        const int n = r >> 1;
        const size_t loff = (size_t)n * NCOLS + g * NVARS;
        const size_t goff = (size_t)r * NVARS;

        float lg[5], u5[5];
#pragma unroll
        for (int j = 0; j < 5; ++j) u5[j] = gu[goff + lane + j * 64];
#pragma unroll
        for (int j = 0; j < 5; ++j) lg[j] = bf16_to_f32(Lg[loff + lane + j * 64]);

        // argmax over key = lg - log(-log(u)), first-index tie-break
        float bk = lg[0] - __logf(-__logf(u5[0]));
        int bi = lane;
#pragma unroll
        for (int j = 1; j < 5; ++j) {
            const float kj = lg[j] - __logf(-__logf(u5[j]));
            const int v = lane + j * 64;
            if (kj > bk) { bk = kj; bi = v; }
        }
#pragma unroll
        for (int sh = 32; sh > 0; sh >>= 1) {
            const float ok = __shfl_xor(bk, sh);
            const int oi = __shfl_xor(bi, sh);
            if (ok > bk || (ok == bk && oi < bi)) { bk = ok; bi = oi; }
        }

        // softmax without max-subtraction (logits bounded ~|3.5|)
        float p[5], sume = 0.f;
#pragma unroll
        for (int j = 0; j < 5; ++j) { p[j] = __expf(lg[j]); sume += p[j]; }
#pragma unroll
        for (int sh = 32; sh > 0; sh >>= 1) sume += __shfl_xor(sume, sh);
        const float inv = 1.f / sume;
#pragma unroll
        for (int j = 0; j < 5; ++j) macc[j] += p[j] * inv;

        // gather selected codevector (128 f32 -> float2/lane)
        const float2* cvrow =
            reinterpret_cast<const float2*>(cv + (size_t)(g * NVARS + bi) * 128);
        reinterpret_cast<float2*>(out + (size_t)n * CVDIM + g * 128)[lane] = cvrow[lane];
    }

    // block-level marginal reduce: waves 0,2 -> group0; 1,3 -> group1
#pragma unroll
    for (int j = 0; j < 5; ++j) smr[w][lane + j * 64] = macc[j];
    __syncthreads();
    for (int i = tid; i < NVARS; i += 256) {
        atomicAdd(&marginal[i], smr[0][i] + smr[2][i]);
        atomicAdd(&marginal[NVARS + i], smr[1][i] + smr[3][i]);
    }
}

// ---------------- Perplexity finalize ----------------
__global__ void perplexity_kernel(const float* __restrict__ marginal,
                                  float* __restrict__ out)
{
    const int lane = threadIdx.x;
    float h0 = 0.0f, h1 = 0.0f;
    for (int v = lane; v < NVARS; v += 64) {
        const float m0 = marginal[v] * (1.0f / (float)NROWS);
        h0 += m0 * logf(m0 + 1e-7f);
        const float m1 = marginal[NVARS + v] * (1.0f / (float)NROWS);
        h1 += m1 * logf(m1 + 1e-7f);
    }
#pragma unroll
    for (int s = 32; s > 0; s >>= 1) {
        h0 += __shfl_xor(h0, s);
        h1 += __shfl_xor(h1, s);
    }
    if (lane == 0) out[OUT_ELEMS] = expf(-h0) + expf(-h1);
}

extern "C" void kernel_launch(void* const* d_in, const int* in_sizes, int n_in,
                              void* d_out, int out_size, void* d_ws, size_t ws_size,
                              hipStream_t stream) {
    const float* X    = (const float*)d_in[0];   // [8,2048,1024]
    const float* W    = (const float*)d_in[1];   // [640,1024]
    const float* bias = (const float*)d_in[2];   // [640]
    const float* cv   = (const float*)d_in[3];   // [1,640,128]
    const float* gu   = (const float*)d_in[4];   // [32768,320]
    float* out = (float*)d_out;

    ushort* Wbf      = (ushort*)d_ws;                             // 1.31 MB
    ushort* Lg       = Wbf + (size_t)NCOLS * HIDDEN;              // 20.97 MB
    float*  marginal = (float*)(Lg + (size_t)NROWS * NCOLS);      // 2.56 KB

    (void)hipMemsetAsync(marginal, 0, NCOLS * sizeof(float), stream);

    convert_bf16_kernel<<<(NCOLS * HIDDEN / 8 + 255) / 256, 256, 0, stream>>>(
        W, Wbf, NCOLS * HIDDEN / 8);

    gemm_logits_kernel<<<(NROWS / GBM) * (NCOLS / GBN), 256, 0, stream>>>(
        X, Wbf, bias, Lg);

    quantize_kernel<<<(NROWS * 2) / 32, 256, 0, stream>>>(
        Lg, gu, cv, out, marginal);

    perplexity_kernel<<<1, 64, 0, stream>>>(marginal, out);
}